// Round 2
// baseline (286.807 us; speedup 1.0000x reference)
//
#include <hip/hip_runtime.h>

// Problem constants (from reference):
//   x:  [32,16,1,2048] int32  -> 1,048,576 tokens
//   W:  [64, 4096] fp32
//   b:  [64] fp32
//   out:[32,16,2048,64] fp32  = 67,108,864 floats (256 MiB)
#define VOCAB   4096
#define F_DIM   64
#define TOKENS  (32 * 16 * 2048)

// Native vector type: __builtin_nontemporal_store accepts this (HIP's
// float4 struct is rejected by the builtin on gfx950).
typedef float f32x4 __attribute__((ext_vector_type(4)));

// Step 1: build WT[v][f] = W[f][v] + b[f]   (bias folded in).
// 1 MiB table, L2/L3 resident for the gather kernel.
__global__ void build_wt_kernel(const float* __restrict__ W,
                                const float* __restrict__ bias,
                                float* __restrict__ WT) {
    int tid = blockIdx.x * blockDim.x + threadIdx.x;   // one per WT element
    int f = tid & (F_DIM - 1);
    int v = tid >> 6;                                   // / F_DIM
    // WT write is fully coalesced; W read is strided (16 KiB) but total
    // traffic is only 1 MiB — negligible vs the 256 MiB main write.
    WT[tid] = W[f * VOCAB + v] + bias[f];
}

// Step 2: gather. 16 lanes per token, one float4 (16 B) per lane.
// A wave64 covers 4 consecutive tokens -> 1 KiB contiguous store,
// and 4 contiguous 256 B reads from WT (L2-hit).
__global__ void gather_kernel(const int* __restrict__ idx,
                              const f32x4* __restrict__ WT4,
                              f32x4* __restrict__ out4) {
    unsigned tid = blockIdx.x * blockDim.x + threadIdx.x;
    unsigned token = tid >> 4;          // 16 threads per token
    unsigned q     = tid & 15;          // which float4 of the 16
    int id = idx[token];                // 16 lanes same addr -> broadcast
    f32x4 v = WT4[(unsigned)id * 16u + q];
    // Nontemporal store: output is write-once, keep WT hot in L2.
    __builtin_nontemporal_store(v, &out4[tid]);
}

extern "C" void kernel_launch(void* const* d_in, const int* in_sizes, int n_in,
                              void* d_out, int out_size, void* d_ws, size_t ws_size,
                              hipStream_t stream) {
    const int*   x = (const int*)d_in[0];     // [B,C,1,N] int32
    const float* W = (const float*)d_in[1];   // [F_DIM, VOCAB]
    const float* b = (const float*)d_in[2];   // [F_DIM]
    float* out = (float*)d_out;
    float* WT  = (float*)d_ws;                // VOCAB*F_DIM floats = 1 MiB

    // Build the transposed (bias-folded) table.
    {
        int total = VOCAB * F_DIM;            // 262,144
        int block = 256;
        build_wt_kernel<<<total / block, block, 0, stream>>>(W, b, WT);
    }

    // Gather: TOKENS * 16 threads, each one float4.
    {
        unsigned total = (unsigned)TOKENS * 16u;   // 16,777,216
        int block = 256;
        gather_kernel<<<total / block, block, 0, stream>>>(
            x, (const f32x4*)WT, (f32x4*)out);
    }
}